// Round 4
// baseline (450.177 us; speedup 1.0000x reference)
//
#include <hip/hip_runtime.h>

// ---------------------------------------------------------------------------
// LayerStacks (NNUE-style) on MI355X.
//   h0 = clamp01( x @ (w0[b]+w_fact)^T + b0[b] )   // 1024 -> 32, bf16 MFMA
//   h1 = clamp01( h0 @ w1[b]^T + b1[b] )           // 32 -> 32,  fp32 VALU
//   out = h1 @ w2[b]^T + b2[b]                     // 32 -> 1,   fp32 VALU
// R2/R3 finding: any sorted-row gather is DRAM-activate bound (256-B channel
// interleave makes even 4-KB gathers random per channel). R4: NO sort —
// stream x in natural order (block = 32 contiguous rows = 128 KB sequential),
// MFMA *all 8 buckets* (compute is ~14 us vs 41 us memory floor, hidden),
// epilogue selects each row's bucket from ls_indices directly.
// ---------------------------------------------------------------------------

#define B_ROWS 65536
#define LK     1024       // 2*L1
#define TILE   32
#define NBLK   (B_ROWS / TILE)   // 2048
#define SROW   2056       // LDS row stride bytes (1028 bf16): 2-way-free banks

// ws layout: wB at offset 0: bf16 B-frags of (w0+w_fact), 8 buckets * 4096
// uint4; frag c*64+l holds W[bkt*32 + (l&31)][16c + 8*(l>>5) .. +8]
typedef short  short8  __attribute__((ext_vector_type(8)));
typedef float  f32x16  __attribute__((ext_vector_type(16)));

__device__ __forceinline__ unsigned pkbf(float a, float b) {
    // round-to-nearest-even fp32 -> bf16, packed pair
    unsigned ua = __float_as_uint(a), ub = __float_as_uint(b);
    ua = (ua + 0x7FFFu + ((ua >> 16) & 1u)) >> 16;
    ub = (ub + 0x7FFFu + ((ub >> 16) & 1u)) >> 16;
    return (ua & 0xFFFFu) | (ub << 16);
}

// ls_indices may be int32 or int64. If int64, the high words (odd int32
// slots) of the first 64 elements are all zero (values 0..7). Deterministic.
__device__ __forceinline__ bool detect_i64(const int* p) {
    int acc = 0;
#pragma unroll
    for (int i = 0; i < 64; ++i) acc |= p[2 * i + 1];
    return acc == 0;
}

__device__ __forceinline__ int load_bucket(const int* p, int r, bool i64) {
    return (i64 ? p[2 * r] : p[r]) & 7;
}

// --- K1: weight prep ---------------------------------------------------------
// Build bf16 B-fragments of (w0+w_fact) for all 8 buckets. 1 frag per thread.
__global__ __launch_bounds__(1024) void k_prep(
    const float* __restrict__ w0, const float* __restrict__ wf,
    uint4* __restrict__ wB)
{
    int f = blockIdx.x * 1024 + threadIdx.x;   // 32768 frags
    int b   = f >> 12;
    int i12 = f & 4095;
    int kc  = i12 >> 8;
    int i8  = i12 & 255;
    int n   = i8 & 31;
    int khi = i8 >> 5;
    int k = kc * 64 + khi * 8;
    const float* p0 = w0 + (size_t)(b * 32 + n) * LK + k;
    const float* pf = wf + (size_t)n * LK + k;
    float v[8];
#pragma unroll
    for (int j = 0; j < 8; ++j) v[j] = p0[j] + pf[j];
    uint4 o;
    o.x = pkbf(v[0], v[1]); o.y = pkbf(v[2], v[3]);
    o.z = pkbf(v[4], v[5]); o.w = pkbf(v[6], v[7]);
    wB[f] = o;
}

// --- K2: main fused kernel ---------------------------------------------------
// Block = 256 thr = 4 waves; 32 contiguous rows, full K=1024 in LDS (bf16,
// stride SROW). Wave w MFMAs buckets {2w, 2w+1} over full K (64 chunks).
// Epilogue: per-row bucket from ls_indices, layers 1+2 in fp32.
__global__ __launch_bounds__(256, 2) void k_main(
    const float* __restrict__ x, const int* __restrict__ idx,
    const uint4* __restrict__ wB,
    const float* __restrict__ b0, const float* __restrict__ w1,
    const float* __restrict__ b1, const float* __restrict__ w2,
    const float* __restrict__ b2, float* __restrict__ out)
{
    __shared__ __align__(16) unsigned char smem[TILE * SROW];  // 65792 B
    float* hb = (float*)smem;   // epilogue alias: hb[b][m][n] = b*1152+m*36+n

    int g    = blockIdx.x;
    int row0 = g * TILE;
    int t    = threadIdx.x;
    int lane = t & 63;
    int wv   = t >> 6;

    // ---- stage 32 contiguous rows (128 KB, fully sequential) ----
    const float4* src = (const float4*)(x + (size_t)row0 * LK);
#pragma unroll
    for (int j0 = 0; j0 < 32; j0 += 8) {
        float4 v[8];
#pragma unroll
        for (int jj = 0; jj < 8; ++jj)
            v[jj] = src[(j0 + jj) * 256 + t];          // iter jj = one 4-KB row
#pragma unroll
        for (int jj = 0; jj < 8; ++jj) {
            uint2 o;
            o.x = pkbf(v[jj].x, v[jj].y);
            o.y = pkbf(v[jj].z, v[jj].w);
            *(uint2*)(smem + (j0 + jj) * SROW + t * 8) = o;  // b64, 2-way free
        }
    }
    __syncthreads();

    // ---- MFMA: wave wv computes buckets 2wv and 2wv+1 over full K ----
    const unsigned char* Ab = smem + (size_t)(lane & 31) * SROW + 16 * (lane >> 5);
    const uint4* wB0 = wB + (size_t)(2 * wv) * 4096;
    const uint4* wB1 = wB0 + 4096;

    f32x16 acc0, acc1;
#pragma unroll
    for (int i = 0; i < 16; ++i) { acc0[i] = 0.0f; acc1[i] = 0.0f; }

    union UA { uint2 h[2]; short8 s; };
    union UB { uint4 u;    short8 s; };
#pragma unroll 4
    for (int c = 0; c < 64; ++c) {
        UA ua;
        ua.h[0] = *(const uint2*)(Ab + 32 * c);        // ds_read_b64 x2
        ua.h[1] = *(const uint2*)(Ab + 32 * c + 8);
        UB u0, u1;
        u0.u = wB0[c * 64 + lane];                     // L2-resident weights
        u1.u = wB1[c * 64 + lane];
        acc0 = __builtin_amdgcn_mfma_f32_32x32x16_bf16(ua.s, u0.s, acc0, 0, 0, 0);
        acc1 = __builtin_amdgcn_mfma_f32_32x32x16_bf16(ua.s, u1.s, acc1, 0, 0, 0);
    }
    __syncthreads();   // all A reads done; safe to alias hb over smem

    // ---- C (+bias, clamp) -> hb[bucket][m][n] ----
#pragma unroll
    for (int pp = 0; pp < 2; ++pp) {
        int bk = 2 * wv + pp;
        float bv = b0[bk * 32 + (lane & 31)];
#pragma unroll
        for (int r = 0; r < 16; ++r) {
            int m = (r & 3) + 8 * (r >> 2) + 4 * (lane >> 5);
            float h = (pp ? acc1[r] : acc0[r]) + bv;
            h = fminf(fmaxf(h, 0.0f), 1.0f);
            hb[bk * 1152 + m * 36 + (lane & 31)] = h;
        }
    }
    __syncthreads();

    // ---- layers 1+2 (fp32): 8 threads per row; thread covers 4 of 32 j2 ----
    bool i64 = detect_i64(idx);
    int r   = t >> 3;
    int sub = t & 7;
    int bk  = load_bucket(idx, row0 + r, i64);
    const float4* hr = (const float4*)(hb + bk * 1152 + r * 36);
    float4 ha[8];
#pragma unroll
    for (int q = 0; q < 8; ++q) ha[q] = hr[q];
    const float* w1b = w1 + (size_t)bk * 1024;
    const float* b1b = b1 + bk * 32;
    const float* w2b = w2 + bk * 32;
    float partial = 0.0f;
#pragma unroll
    for (int jj = 0; jj < 4; ++jj) {
        int j2 = sub * 4 + jj;
        const float4* wr = (const float4*)&w1b[j2 * 32];
        float s = b1b[j2];
#pragma unroll
        for (int q = 0; q < 8; ++q) {
            float4 w4 = wr[q];
            s += ha[q].x * w4.x + ha[q].y * w4.y + ha[q].z * w4.z + ha[q].w * w4.w;
        }
        s = fminf(fmaxf(s, 0.0f), 1.0f);
        partial += s * w2b[j2];
    }
    partial += __shfl_xor(partial, 1);
    partial += __shfl_xor(partial, 2);
    partial += __shfl_xor(partial, 4);
    if (sub == 0) out[row0 + r] = partial + b2[bk];
}

// ---------------------------------------------------------------------------
extern "C" void kernel_launch(void* const* d_in, const int* in_sizes, int n_in,
                              void* d_out, int out_size, void* d_ws, size_t ws_size,
                              hipStream_t stream) {
    const float* x   = (const float*)d_in[0];
    const int*   lsi = (const int*)  d_in[1];
    const float* wf  = (const float*)d_in[2];
    const float* w0  = (const float*)d_in[3];
    const float* b0  = (const float*)d_in[4];
    const float* w1  = (const float*)d_in[5];
    const float* b1  = (const float*)d_in[6];
    const float* w2  = (const float*)d_in[7];
    const float* b2  = (const float*)d_in[8];
    float* out = (float*)d_out;

    uint4* wB = (uint4*)d_ws;

    k_prep<<<32, 1024, 0, stream>>>(w0, wf, wB);
    k_main<<<NBLK, 256, 0, stream>>>(x, lsi, wB, b0, w1, b1, w2, b2, out);
}